// Round 1
// 296.036 us; speedup vs baseline: 1.0725x; 1.0725x over previous
//
#include <hip/hip_runtime.h>
#include <hip/hip_bf16.h>

#define B_N 8192
#define M_N 3129
#define M_PAD 3200
#define D_N 512

// ce streaming: each wave owns a contiguous span of 3072 floats (12 float4
// wave-loads). 3072 < 3129 => at most ONE row boundary per span => 2 buckets.
// 8192*3129 floats = 25,632,768 = 8344 spans/array exactly.
#define CE_L 12
#define CE_SPAN (CE_L * 256)     // 3072 floats
#define CE_WPA 8344              // spans per array
#define CE_WTOT (2 * CE_WPA)     // 16688 total spans
#define CE_BLOCKS (CE_WTOT / 4)  // 4172 blocks (4 waves/block)

// Kernel A (prep + zero): normalize g/a, obj rows, zero accumulator region.
#define PREP_G_BLOCKS   (B_N / 4)      // 2048
#define PREP_A_BLOCKS   (M_PAD / 4)    // 800
#define PREP_OBJ_BLOCKS (B_N / 4)      // 2048
#define ZERO_FLOATS (3 * B_N + 8)      // den[8192]|rowsum[16384]|acc[4]|cnt[4]
#define ZERO_BLOCKS 25                 // 25*256*4 = 25600 >= 24584
#define A_BLOCKS (PREP_G_BLOCKS + PREP_A_BLOCKS + PREP_OBJ_BLOCKS + ZERO_BLOCKS)

// Kernel B (fused gemm + ALL ce + pos), role-interleaved:
//   blk%5==2        -> GEMM tile   (8000/5 = 1600 tiles exactly)
//   other: first 4172 -> CE block, remaining 2228 -> pos block (guarded)
#define GEMM_TILES ((M_PAD / 128) * (B_N / 128))   // 25*64 = 1600
#define B_BLOCKS 8000
#define POS_BLOCKS_B (B_BLOCKS - GEMM_TILES - CE_BLOCKS)  // 2228

#define GLOBAL_AS __attribute__((address_space(1)))
#define LDS_AS __attribute__((address_space(3)))

typedef __bf16 bf16x8 __attribute__((ext_vector_type(8)));
typedef float f32x4 __attribute__((ext_vector_type(4)));

__device__ __forceinline__ f32x4 nt_load4(const float* p) {
  return __builtin_nontemporal_load((const f32x4*)p);
}

// ---------------------------------------------------------------------------
// One ce span: contiguous 3072 floats, 2 row-buckets split by a wave-uniform
// bound, single end-of-wave shfl reduction, <=2 atomics. Loads are
// NON-TEMPORAL: this 205 MB stream is single-use and must not evict the g/a
// panels the GEMM re-reads from L3.
// rowsum layout: [0..8191] = logits_q rows, [8192..16383] = logits_rubi.
__device__ __forceinline__ void ce_span(
    int gw, const float* __restrict__ lq, const float* __restrict__ lr,
    float* __restrict__ rowsum) {
  const int lane = threadIdx.x & 63;
  const int aidx = (gw >= CE_WPA) ? 1 : 0;
  const unsigned wl = (unsigned)(gw - aidx * CE_WPA);
  const unsigned f0 = wl * (unsigned)CE_SPAN;          // span start (flat)
  const unsigned r0 = f0 / (unsigned)M_N;              // magic-mul div
  const unsigned b1 = (r0 + 1u) * (unsigned)M_N;       // wave-uniform bound
  const float* base = aidx ? lr : lq;
  const float* p = base + f0 + (unsigned)lane * 4u;

  f32x4 buf[6];
#pragma unroll
  for (int i = 0; i < 6; ++i) buf[i] = nt_load4(p + i * 256);

  float a0 = 0.f, a1 = 0.f;
  const unsigned fbase = f0 + (unsigned)lane * 4u;
#pragma unroll
  for (int i = 0; i < CE_L; ++i) {
    f32x4 v = buf[i % 6];
    if (i + 6 < CE_L) buf[i % 6] = nt_load4(p + (i + 6) * 256);
    unsigned f = fbase + (unsigned)i * 256u;
    float e0 = __expf(v.x), e1 = __expf(v.y), e2 = __expf(v.z), e3 = __expf(v.w);
    float lo = 0.f, hi = 0.f;
    if (f + 0u < b1) lo += e0; else hi += e0;
    if (f + 1u < b1) lo += e1; else hi += e1;
    if (f + 2u < b1) lo += e2; else hi += e2;
    if (f + 3u < b1) lo += e3; else hi += e3;
    a0 += lo; a1 += hi;
  }
  for (int o = 1; o < 64; o <<= 1) {
    a0 += __shfl_xor(a0, o);
    a1 += __shfl_xor(a1, o);
  }
  if (lane == 0) {
    float* rs = rowsum + (aidx ? B_N : 0);
    atomicAdd(rs + r0, a0);
    if (a1 != 0.f) atomicAdd(rs + r0 + 1, a1);  // exact 0 iff no boundary
  }
}

__device__ __forceinline__ void normalize_row(
    const float* __restrict__ x, __bf16* __restrict__ y,
    int row, int nrows_src, int lane) {
  bf16x8 out;
  if (row >= nrows_src) {
    for (int j = 0; j < 8; ++j) out[j] = (__bf16)0.0f;
    *(bf16x8*)(y + (size_t)row * D_N + lane * 8) = out;
    return;
  }
  const float* xr = x + (size_t)row * D_N + lane * 8;
  f32x4 v0 = *(const f32x4*)xr;
  f32x4 v1 = *(const f32x4*)(xr + 4);
  float s = v0.x*v0.x + v0.y*v0.y + v0.z*v0.z + v0.w*v0.w
          + v1.x*v1.x + v1.y*v1.y + v1.z*v1.z + v1.w*v1.w;
  for (int o = 1; o < 64; o <<= 1) s += __shfl_xor(s, o);
  float rn = 1.0f / fmaxf(sqrtf(s), 1e-8f);
  float vals[8] = {v0.x, v0.y, v0.z, v0.w, v1.x, v1.y, v1.z, v1.w};
  for (int j = 0; j < 8; ++j) out[j] = (__bf16)(vals[j] * rn);
  *(bf16x8*)(y + (size_t)row * D_N + lane * 8) = out;
}

// ---------------------------------------------------------------------------
// Kernel A: prep only (normalize g/a, obj) + zero den/rowsum/acc/cnt with
// plain stores (replaces the hipMemsetAsync node). ~66 MB traffic -> ~12 us.
__global__ __launch_bounds__(256) void a_prep_kernel(
    const float* __restrict__ mm_proj, const float* __restrict__ ans_emb,
    const float* __restrict__ v_max, const float* __restrict__ mm,
    __bf16* __restrict__ g, __bf16* __restrict__ a,
    float* __restrict__ obj, float* __restrict__ zbase) {
  int blk = blockIdx.x;
  int wid = threadIdx.x >> 6, lane = threadIdx.x & 63;
  if (blk < PREP_G_BLOCKS) {
    normalize_row(mm_proj, g, blk * 4 + wid, B_N, lane);
  } else if (blk < PREP_G_BLOCKS + PREP_A_BLOCKS) {
    normalize_row(ans_emb, a, (blk - PREP_G_BLOCKS) * 4 + wid, M_N, lane);
  } else if (blk < PREP_G_BLOCKS + PREP_A_BLOCKS + PREP_OBJ_BLOCKS) {
    int b = (blk - PREP_G_BLOCKS - PREP_A_BLOCKS) * 4 + wid;
    const float* vr = v_max + (size_t)b * D_N + lane * 8;
    const float* mr = mm + (size_t)b * D_N + lane * 8;
    f32x4 a0 = nt_load4(vr), a1 = nt_load4(vr + 4);   // single-use: nt
    f32x4 b0 = nt_load4(mr), b1 = nt_load4(mr + 4);
    float sv = a0.x*a0.x + a0.y*a0.y + a0.z*a0.z + a0.w*a0.w
             + a1.x*a1.x + a1.y*a1.y + a1.z*a1.z + a1.w*a1.w;
    float sm = b0.x*b0.x + b0.y*b0.y + b0.z*b0.z + b0.w*b0.w
             + b1.x*b1.x + b1.y*b1.y + b1.z*b1.z + b1.w*b1.w;
    float sd = a0.x*b0.x + a0.y*b0.y + a0.z*b0.z + a0.w*b0.w
             + a1.x*b1.x + a1.y*b1.y + a1.z*b1.z + a1.w*b1.w;
    for (int o = 1; o < 64; o <<= 1) {
      sv += __shfl_xor(sv, o);
      sm += __shfl_xor(sm, o);
      sd += __shfl_xor(sd, o);
    }
    if (lane == 0) {
      float dist = sd / (fmaxf(sqrtf(sv), 1e-8f) * fmaxf(sqrtf(sm), 1e-8f));
      obj[b] = 1.0f - dist;
    }
  } else {
    int zb = blk - (PREP_G_BLOCKS + PREP_A_BLOCKS + PREP_OBJ_BLOCKS);
    int idx = (zb * 256 + threadIdx.x) * 4;
    if (idx < ZERO_FLOATS) *(f32x4*)(zbase + idx) = f32x4{0.f, 0.f, 0.f, 0.f};
  }
}

// ---------------------------------------------------------------------------
__device__ __forceinline__ void gemm_stage(
    const __bf16* __restrict__ g, const __bf16* __restrict__ a,
    __bf16* As, __bf16* Bs, int t, int brow0, int mrow0, int k0) {
#pragma unroll
  for (int i = 0; i < 2; ++i) {
    int s = t + i * 256;
    int row = s >> 2;
    int kq = (s & 3) << 3;
    const __bf16* ga = g + (size_t)(brow0 + row) * D_N + (k0 + kq);
    __builtin_amdgcn_global_load_lds((const GLOBAL_AS void*)ga,
                                     (LDS_AS void*)(As + s * 8), 16, 0, 0);
    const __bf16* gb = a + (size_t)(mrow0 + row) * D_N + (k0 + kq);
    __builtin_amdgcn_global_load_lds((const GLOBAL_AS void*)gb,
                                     (LDS_AS void*)(Bs + s * 8), 16, 0, 0);
  }
}

// Kernel B: GEMM (dbuf, 1 barrier/K-step) + ALL ce + pos, role-interleaved so
// every CU hosts ~1 GEMM block + 4 streaming blocks for the whole kernel:
// CE's streaming loads fill the GEMM's load-latency stalls, GEMM's MFMA fills
// CE's memory stalls. pos recomputes normalization with the EXACT op sequence
// of normalize_row => bit-identical bf16 => consistent with the MFMA d_logit.
__global__ __launch_bounds__(256) void b_fused_kernel(
    const __bf16* __restrict__ g, const __bf16* __restrict__ a,
    const int* __restrict__ cid,
    const float* __restrict__ mm_proj, const float* __restrict__ ans_emb,
    const float* __restrict__ lq, const float* __restrict__ lr,
    float* __restrict__ den, float* __restrict__ pos,
    float* __restrict__ rowsum) {
  __shared__ __bf16 As[2][128 * 32];
  __shared__ __bf16 Bs[2][128 * 32];
  const int t = threadIdx.x;
  const int lane = t & 63;
  const int wid = t >> 6;

  const int blk = blockIdx.x;
  const int mod = blk % 5;
  const int div5 = blk / 5;

  if (mod == 2) {
    // ---- GEMM tile role (1600 tiles) ----
    const int tile = div5;
    const int brow0 = (tile / (M_PAD / 128)) * 128;
    const int mrow0 = (tile % (M_PAD / 128)) * 128;
    const int wrow = wid >> 1;      // 0..1
    const int wcol = wid & 1;       // 0..1
    const int r = lane & 15;
    const int quad = lane >> 4;

    f32x4 acc[4][4];
    for (int i = 0; i < 4; ++i)
      for (int j = 0; j < 4; ++j)
        acc[i][j] = f32x4{0.f, 0.f, 0.f, 0.f};

    // prologue: stage K-step 0 into buf 0, drain, barrier
    gemm_stage(g, a, &As[0][0], &Bs[0][0], t, brow0, mrow0, 0);
    int cur = 0;
    __syncthreads();

    for (int ks = 0; ks < D_N / 32; ++ks) {
      // issue next K-step's loads BEFORE consuming current buffer:
      // latency hides under the ds_read+MFMA phase below.
      if (ks + 1 < D_N / 32)
        gemm_stage(g, a, &As[cur ^ 1][0], &Bs[cur ^ 1][0], t, brow0, mrow0,
                   (ks + 1) * 32);
      bf16x8 af[4], bfr[4];
#pragma unroll
      for (int i = 0; i < 4; ++i)
        af[i] = *(const bf16x8*)(&As[cur][(wrow * 64 + i * 16 + r) * 32 + quad * 8]);
#pragma unroll
      for (int j = 0; j < 4; ++j)
        bfr[j] = *(const bf16x8*)(&Bs[cur][(wcol * 64 + j * 16 + r) * 32 + quad * 8]);
#pragma unroll
      for (int i = 0; i < 4; ++i)
#pragma unroll
        for (int j = 0; j < 4; ++j)
          acc[i][j] = __builtin_amdgcn_mfma_f32_16x16x32_bf16(af[i], bfr[j],
                                                              acc[i][j], 0, 0, 0);
      // one barrier per step: drains this step's stage (next buf ready) and
      // guarantees everyone finished reading cur before it's overwritten.
      __syncthreads();
      cur ^= 1;
    }

    // C/D layout: col = lane&15, row = quad*4 + reg.
    for (int i = 0; i < 4; ++i) {
      for (int reg = 0; reg < 4; ++reg) {
        float s = 0.0f;
        for (int j = 0; j < 4; ++j) {
          int m = mrow0 + wcol * 64 + j * 16 + r;
          if (m < M_N) s += __expf(acc[i][j][reg]);
        }
        s += __shfl_xor(s, 1);
        s += __shfl_xor(s, 2);
        s += __shfl_xor(s, 4);
        s += __shfl_xor(s, 8);
        if (r == 0) {
          int b = brow0 + wrow * 64 + i * 16 + quad * 4 + reg;
          atomicAdd(den + b, s);
        }
      }
    }
    return;
  }

  // non-GEMM roles: mod in {0,1,3,4} -> local 0..3
  const int other = div5 * 4 + mod - (mod > 2 ? 1 : 0);
  if (other < CE_BLOCKS) {
    ce_span(other * 4 + wid, lq, lr, rowsum);
    return;
  }

  // ---- pos role ----
  {
    int b = (other - CE_BLOCKS) * 4 + wid;
    if (b >= B_N) return;  // wave-uniform guard (2228*4 > 8192)
    int label = cid[b];
    const float* xr = mm_proj + (size_t)b * D_N + lane * 8;
    f32x4 v0 = *(const f32x4*)xr, v1 = *(const f32x4*)(xr + 4);
    const float* yr = ans_emb + (size_t)label * D_N + lane * 8;
    f32x4 w0 = *(const f32x4*)yr, w1 = *(const f32x4*)(yr + 4);
    float sg = v0.x*v0.x + v0.y*v0.y + v0.z*v0.z + v0.w*v0.w
             + v1.x*v1.x + v1.y*v1.y + v1.z*v1.z + v1.w*v1.w;
    float sa = w0.x*w0.x + w0.y*w0.y + w0.z*w0.z + w0.w*w0.w
             + w1.x*w1.x + w1.y*w1.y + w1.z*w1.z + w1.w*w1.w;
    for (int o = 1; o < 64; o <<= 1) {
      sg += __shfl_xor(sg, o);
      sa += __shfl_xor(sa, o);
    }
    float rng = 1.0f / fmaxf(sqrtf(sg), 1e-8f);
    float rna = 1.0f / fmaxf(sqrtf(sa), 1e-8f);
    float gv[8] = {v0.x, v0.y, v0.z, v0.w, v1.x, v1.y, v1.z, v1.w};
    float av[8] = {w0.x, w0.y, w0.z, w0.w, w1.x, w1.y, w1.z, w1.w};
    float d = 0.0f;
    for (int j = 0; j < 8; ++j)
      d += (float)(__bf16)(gv[j] * rng) * (float)(__bf16)(av[j] * rna);
    for (int o = 1; o < 64; o <<= 1) d += __shfl_xor(d, o);
    if (lane == 0) pos[b] = d;
  }
}

// ---------------------------------------------------------------------------
// Kernel C: per-row losses -> acc[0..3], combine folded in via arrival
// counter (device-scope atomics; __threadfence release before arrival, RMW
// reads for acquire). Saves the separate combine launch.
__global__ __launch_bounds__(256) void c_final_kernel(
    const float* __restrict__ den, const float* __restrict__ pos,
    const float* __restrict__ rowsum,
    const float* __restrict__ lq, const float* __restrict__ lr,
    const int* __restrict__ cid, const float* __restrict__ obj,
    float* __restrict__ acc, float* __restrict__ out) {
  int b = blockIdx.x * 256 + threadIdx.x;  // 32*256 == B_N exactly
  int lab = cid[b];
  float xq = lq[(size_t)b * M_N + lab];
  float xr = lr[(size_t)b * M_N + lab];
  float s_nce = logf(den[b]) - pos[b];
  float s_ceq = logf(rowsum[b]) - xq;
  float s_cer = logf(rowsum[B_N + b]) - xr;
  float s_obj = obj[b];
  for (int o = 1; o < 64; o <<= 1) {
    s_nce += __shfl_xor(s_nce, o);
    s_ceq += __shfl_xor(s_ceq, o);
    s_cer += __shfl_xor(s_cer, o);
    s_obj += __shfl_xor(s_obj, o);
  }
  __shared__ float red[4][4];
  int wid = threadIdx.x >> 6;
  if ((threadIdx.x & 63) == 0) {
    red[wid][0] = s_nce; red[wid][1] = s_ceq;
    red[wid][2] = s_cer; red[wid][3] = s_obj;
  }
  __syncthreads();
  if (threadIdx.x < 4) {
    float v = red[0][threadIdx.x] + red[1][threadIdx.x]
            + red[2][threadIdx.x] + red[3][threadIdx.x];
    atomicAdd(acc + threadIdx.x, v);
  }
  if (threadIdx.x == 0) {
    __threadfence();  // release: acc adds (lanes 0-3, same wave) visible first
    unsigned prev = atomicAdd((unsigned*)(acc + 4), 1u);
    if (prev == 31u) {  // last arriver: all 32 blocks' adds are visible
      float nce = atomicAdd(acc + 0, 0.0f) / (float)B_N;
      float ceq = atomicAdd(acc + 1, 0.0f) / (float)B_N;
      float cer = atomicAdd(acc + 2, 0.0f) / (float)B_N;
      float ob  = atomicAdd(acc + 3, 0.0f) / (float)B_N;
      float fusion = (cer + ob + nce) * (1.0f / 3.0f);
      out[0] = fusion + ceq;  // question_loss_weight = 1.0
      out[1] = fusion;
      out[2] = ceq;
    }
  }
}

// ---------------------------------------------------------------------------
extern "C" void kernel_launch(void* const* d_in, const int* in_sizes, int n_in,
                              void* d_out, int out_size, void* d_ws, size_t ws_size,
                              hipStream_t stream) {
  const float* mm_proj     = (const float*)d_in[0];
  const float* ans_emb     = (const float*)d_in[1];
  const float* v_max       = (const float*)d_in[2];
  const float* mm          = (const float*)d_in[3];
  const float* logits_q    = (const float*)d_in[4];
  const float* logits_rubi = (const float*)d_in[5];
  const int*   cid         = (const int*)d_in[6];
  float* out = (float*)d_out;

  // Workspace layout (16B-aligned):
  //   g_bf16 : 8192*512*2 = 8,388,608 B
  //   a_bf16 : 3200*512*2 = 3,276,800 B
  //   zero region: den[8192] | rowsum[16384] | acc[4] | cnt[4]  (kernel A)
  //   pos[8192], obj[8192]
  char* ws = (char*)d_ws;
  __bf16* g = (__bf16*)ws;
  __bf16* a = (__bf16*)(ws + 8388608);
  float* den    = (float*)(ws + 8388608 + 3276800);
  float* rowsum = den + B_N;
  float* acc    = rowsum + 2 * B_N;   // acc[0..3], cnt at acc[4]
  float* pos    = acc + 8;
  float* obj    = pos + B_N;

  a_prep_kernel<<<A_BLOCKS, 256, 0, stream>>>(
      mm_proj, ans_emb, v_max, mm, g, a, obj, den);
  b_fused_kernel<<<B_BLOCKS, 256, 0, stream>>>(
      g, a, cid, mm_proj, ans_emb, logits_q, logits_rubi, den, pos, rowsum);
  c_final_kernel<<<B_N / 256, 256, 0, stream>>>(
      den, pos, rowsum, logits_q, logits_rubi, cid, obj, acc, out);
}